// Round 18
// baseline (272.479 us; speedup 1.0000x reference)
//
#include <hip/hip_runtime.h>

#define NB 16   // batch
#define NA 6    // actions

typedef __attribute__((ext_vector_type(8))) short short8;
typedef __attribute__((ext_vector_type(4))) short short4_;
typedef __attribute__((ext_vector_type(4))) float f32x4;
typedef __attribute__((ext_vector_type(4))) unsigned uint4_;
typedef __attribute__((ext_vector_type(2))) unsigned uint2_;

__device__ __forceinline__ short tobf(float f) {
    unsigned u = __builtin_bit_cast(unsigned, f);
    u += 0x7FFF + ((u >> 16) & 1);
    return (short)(u >> 16);
}
__device__ __forceinline__ float frombf(short s) {
    unsigned u = ((unsigned)(unsigned short)s) << 16;
    return __builtin_bit_cast(float, u);
}
// packed f32x2 -> bf16x2, RNE (single HW instruction)
__device__ __forceinline__ unsigned cvtpk(float a, float b) {
    unsigned r;
    asm("v_cvt_pk_bf16_f32 %0, %1, %2" : "=v"(r) : "v"(a), "v"(b));
    return r;
}

// ---------------- per-layer weight pack helper ----------------
template<int CIN, int COUT>
__device__ __forceinline__ void pack_one(const float* __restrict__ w, const float* __restrict__ bias,
                                         int a, int b, short* __restrict__ dst, int j) {
    constexpr int KTOT = 25 * CIN;
    constexpr int KPAD = (KTOT + 31) & ~31;
    if (j >= COUT * KPAD) return;
    int oc = j / KPAD, k = j - oc * KPAD;
    float v = 0.f;
    if (k < KTOT) {
        int pos = k / CIN, ci = k - pos * CIN;
        int ky = pos / 5, kx = pos - ky * 5;
        int od = ((oc * CIN + ci) * 5 + ky) * 5 + kx;
        v = w[(size_t)od * NA + a] + bias[od];
    }
    dst[((size_t)(b * (KPAD / 8) + (k >> 3)) * COUT + oc) * 8 + (k & 7)] = tobf(v);
}

// conv1: packed as CIN=8 (4 real channels + 4 zero), COUT=16, KTOT=200, KPAD=224
__device__ __forceinline__ void pack_one8(const float* __restrict__ w, const float* __restrict__ bias,
                                          int a, int b, short* __restrict__ dst, int j) {
    if (j >= 16 * 224) return;
    int oc = j / 224, k = j - oc * 224;
    float v = 0.f;
    if (k < 200) {
        int pos = k >> 3, ci = k & 7;
        if (ci < 4) {
            int ky = pos / 5, kx = pos - ky * 5;
            int od = ((oc * 4 + ci) * 5 + ky) * 5 + kx;
            v = w[(size_t)od * NA + a] + bias[od];
        }
    }
    dst[((size_t)(b * 28 + (k >> 3)) * 16 + oc) * 8 + (k & 7)] = tobf(v);
}

// ---------------- ALL weight gather/pack + bn0 stats partials in one launch ----------------
__global__ void pack_all(const float* __restrict__ w2, const float* __restrict__ b2,
                         const float* __restrict__ w3, const float* __restrict__ b3,
                         const float* __restrict__ w4, const float* __restrict__ b4,
                         const float* __restrict__ w5, const float* __restrict__ b5,
                         const float* __restrict__ w6, const float* __restrict__ b6,
                         const float* __restrict__ w1, const float* __restrict__ b1,
                         const float* __restrict__ w7, const float* __restrict__ b7,
                         const int* __restrict__ action,
                         short* __restrict__ d2, short* __restrict__ d3, short* __restrict__ d4,
                         short* __restrict__ d5, short* __restrict__ d6,
                         short* __restrict__ d1, float* __restrict__ g7,
                         const float* __restrict__ x, float* __restrict__ part0) {
    const int b = blockIdx.y;
    const int bx = blockIdx.x;
    const int t = threadIdx.x;
    if (bx >= 793) {
        // bn0 stats: 64 blocks per batch -> channel c, slice
        const int r = bx - 793;
        const int c = r >> 4, slice = r & 15;
        const float* p = x + (((size_t)(b * 4 + c)) << 16) + slice * 4096;
        float sum = 0.f, sq = 0.f;
        for (int i = t * 4; i < 4096; i += 1024) {
            float4 v = *(const float4*)(p + i);
            sum += (v.x + v.y) + (v.z + v.w);
            sq  += (v.x * v.x + v.y * v.y) + (v.z * v.z + v.w * v.w);
        }
#pragma unroll
        for (int off = 32; off > 0; off >>= 1) {
            sum += __shfl_down(sum, off);
            sq  += __shfl_down(sq, off);
        }
        __shared__ float ssum[4], ssq[4];
        int wv = t >> 6;
        if ((t & 63) == 0) { ssum[wv] = sum; ssq[wv] = sq; }
        __syncthreads();
        if (t == 0) {
            float S = ssum[0] + ssum[1] + ssum[2] + ssum[3];
            float Q = ssq[0] + ssq[1] + ssq[2] + ssq[3];
            atomicAdd(&part0[((size_t)b * 2 + 0) * 4 + c], S);
            atomicAdd(&part0[((size_t)b * 2 + 1) * 4 + c], Q);
        }
        return;
    }
    const int a = action[b];
    if (bx < 26)       pack_one<16, 16>(w2, b2, a, b, d2, bx * 256 + t);
    else if (bx < 78)  pack_one<16, 32>(w3, b3, a, b, d3, (bx - 26) * 256 + t);
    else if (bx < 178) pack_one<32, 32>(w4, b4, a, b, d4, (bx - 78) * 256 + t);
    else if (bx < 378) pack_one<32, 64>(w5, b5, a, b, d5, (bx - 178) * 256 + t);
    else if (bx < 778) pack_one<64, 64>(w6, b6, a, b, d6, (bx - 378) * 256 + t);
    else if (bx < 792) pack_one8(w1, b1, a, b, d1, (bx - 778) * 256 + t);
    else               { g7[(size_t)b * 256 + t] = w7[(size_t)t * NA + a] + b7[t]; }
}

// ---------------- inline BN finalize for 8 channels (from part sums) ----------------
template<int C>
__device__ __forceinline__ void bn_fin8(const float* __restrict__ part,
                                        const float* __restrict__ sc,
                                        const float* __restrict__ bi,
                                        int b, int c0, float invN, f32x4* g, f32x4* e) {
#pragma unroll
    for (int h = 0; h < 2; ++h) {
        f32x4 Sv = *(const f32x4*)&part[((size_t)b * 2 + 0) * C + c0 + h * 4];
        f32x4 Qv = *(const f32x4*)&part[((size_t)b * 2 + 1) * C + c0 + h * 4];
        f32x4 scv = *(const f32x4*)&sc[c0 + h * 4];
        f32x4 biv = *(const f32x4*)&bi[c0 + h * 4];
#pragma unroll
        for (int j = 0; j < 4; ++j) {
            float m = Sv[j] * invN;
            float var = Qv[j] * invN - m * m;
            float gg = scv[j] * rsqrtf(var + 1e-5f);
            g[h][j] = gg;
            e[h][j] = biv[j] - m * gg;
        }
    }
}

// ---------------- bn2 apply + 2x2 avgpool, bf16 -> bf16 (finalize inline) ----------------
__global__ void bnpool2(const short* __restrict__ in, short* __restrict__ out,
                        const float* __restrict__ part, const float* __restrict__ sc,
                        const float* __restrict__ bi) {
    const int b = blockIdx.y;
    const int c8 = threadIdx.x & 1;
    const int c0 = c8 * 8;
    f32x4 g[2], e[2];
    bn_fin8<16>(part, sc, bi, b, c0, 1.f / 65536.f, g, e);
    const size_t bin = (size_t)b * 65536 * 16;
    const size_t bout = (size_t)b * 16384 * 16;
    int total = 16384 * 2;
    int stride = gridDim.x * 256;
    for (int i = blockIdx.x * 256 + threadIdx.x; i < total; i += stride) {
        int opx = i >> 1;
        int ho = opx >> 7, wo = opx & 127;
        size_t p0 = bin + ((size_t)(ho * 2) * 256 + wo * 2) * 16 + c0;
        short8 v00 = *(const short8*)&in[p0];
        short8 v01 = *(const short8*)&in[p0 + 16];
        short8 v10 = *(const short8*)&in[p0 + 4096];
        short8 v11 = *(const short8*)&in[p0 + 4112];
        float f[8];
#pragma unroll
        for (int h = 0; h < 2; ++h)
#pragma unroll
            for (int j = 0; j < 4; ++j) {
                int k = h * 4 + j;
                float fv = (frombf(v00[k]) + frombf(v01[k]) + frombf(v10[k]) + frombf(v11[k])) * 0.25f;
                f[k] = fv * g[h][j] + e[h][j];
            }
        uint4_ vo = {cvtpk(f[0], f[1]), cvtpk(f[2], f[3]), cvtpk(f[4], f[5]), cvtpk(f[6], f[7])};
        *(uint4_*)&out[bout + (size_t)i * 8] = vo;
    }
}

// ---------------- MFMA 5x5 conv v10 (16x16x32): unified contiguous-row staging for all DIL ----------------
// APPLY: 0 = none, 1 = affine, 2 = affine+relu; INMODE: 1 = fp32 NCHW C=4 input, bn0, widen to C=8
template<int CIN, int COUT, int DIL, int WH, int PXB, int ROWS, int OCG, int WAVES, int APPLY, int INMODE = 0>
__global__ void __launch_bounds__(WAVES * 64) convmf8(const short* __restrict__ in,
                                                      const short* __restrict__ wpack,
                                                      short* __restrict__ outp,
                                                      float* __restrict__ partout,
                                                      const float* __restrict__ partin,
                                                      const float* __restrict__ psc,
                                                      const float* __restrict__ pbi,
                                                      float invN) {
    constexpr int PAD   = 2 * DIL;
    constexpr int XT    = PXB + 4 * DIL + 1;
    constexpr int LROWS = ROWS + 4 * DIL;               // contiguous halo rows
    constexpr int KTOT  = 25 * CIN;
    constexpr int KPAD  = (KTOT + 31) & ~31;
    constexpr int NSTEP = KPAD / 32;
    constexpr int CINB  = CIN / 8;
    constexpr int S     = (CIN == 64) ? 0 : (CIN == 32) ? 1 : 2;
    constexpr int NTHR  = WAVES * 64;
    constexpr int PXG   = WAVES / OCG;
    constexpr int OT    = COUT / 16 / OCG;
    constexpr int PT    = ROWS * PXB / (16 * PXG);
    constexpr int LPXB  = (PXB == 16) ? 4 : (PXB == 32) ? 5 : (PXB == 64) ? 6 : 7;
    constexpr int LOGC  = (COUT == 64) ? 6 : (COUT == 32) ? 5 : 4;
    constexpr int CREAL = (INMODE == 1) ? 4 : CIN;
    constexpr int TBYTES = LROWS * XT * CIN * 2;
    static_assert(PXG * 2 * COUT * 4 <= TBYTES, "SP alias fits in T");
    static_assert(NSTEP >= 2, "pipeline depth");
    static_assert(PT * 16 * PXG == ROWS * PXB, "px cover");

    __shared__ __align__(16) char smem[TBYTES + 2 * 64 * 4];
    short* T  = (short*)smem;
    float* GA = (float*)(smem + TBYTES);
    float* BE = GA + 64;
    float* SP = (float*)smem;

    const int b   = blockIdx.z;
    const int y0  = blockIdx.y * ROWS;
    const int x0  = blockIdx.x * PXB;
    const int tid = threadIdx.x;

    if (APPLY) {
        if (tid < CREAL) {
            float S0 = partin[((size_t)b * 2 + 0) * CREAL + tid];
            float Q0 = partin[((size_t)b * 2 + 1) * CREAL + tid];
            float m = S0 * invN;
            float var = Q0 * invN - m * m;
            float g = psc[tid] * rsqrtf(var + 1e-5f);
            GA[tid] = g;
            BE[tid] = pbi[tid] - m * g;
        }
        __syncthreads();
    }

    if constexpr (INMODE == 1) {
        const float* xf = (const float*)in + ((size_t)b << 18);
        float g0 = GA[0], g1 = GA[1], g2 = GA[2], g3 = GA[3];
        float e0 = BE[0], e1 = BE[1], e2 = BE[2], e3 = BE[3];
        for (int idx = tid; idx < LROWS * XT; idx += NTHR) {
            int dyi = idx / XT, xl = idx - dyi * XT;
            int gy = y0 + dyi - PAD;
            int gx = x0 - PAD + xl;
            short8 v = {};
            if ((unsigned)gy < (unsigned)WH && (unsigned)gx < (unsigned)WH) {
                int o = (gy << 8) + gx;
                float f0 = xf[o] * g0 + e0;
                float f1 = xf[o + 65536] * g1 + e1;
                float f2 = xf[o + 131072] * g2 + e2;
                float f3 = xf[o + 196608] * g3 + e3;
                uint4_ uv = {cvtpk(f0, f1), cvtpk(f2, f3), 0u, 0u};
                v = __builtin_bit_cast(short8, uv);
            }
            *(short8*)&T[idx * CIN] = v;
        }
    } else {
        const short* inb = in + (size_t)b * WH * WH * CIN;
        for (int idx = tid; idx < LROWS * XT * CINB; idx += NTHR) {
            int dyi = idx / (XT * CINB);
            int rem = idx - dyi * (XT * CINB);
            int xl = rem / CINB, cic = rem - xl * CINB;
            int gy = y0 + dyi - PAD;
            int gx = x0 - PAD + xl;
            short8 v = {};
            if ((unsigned)gy < (unsigned)WH && (unsigned)gx < (unsigned)WH) {
                v = *(const short8*)&inb[((size_t)gy * WH + gx) * CIN + cic * 8];
                if (APPLY) {
                    float f[8];
#pragma unroll
                    for (int j = 0; j < 8; ++j) f[j] = frombf(v[j]);
                    f32x4 g0 = *(const f32x4*)&GA[cic * 8];
                    f32x4 g1 = *(const f32x4*)&GA[cic * 8 + 4];
                    f32x4 e0 = *(const f32x4*)&BE[cic * 8];
                    f32x4 e1 = *(const f32x4*)&BE[cic * 8 + 4];
#pragma unroll
                    for (int j = 0; j < 4; ++j) {
                        f[j]     = f[j]     * g0[j] + e0[j];
                        f[4 + j] = f[4 + j] * g1[j] + e1[j];
                        if (APPLY == 2) { f[j] = fmaxf(f[j], 0.f); f[4 + j] = fmaxf(f[4 + j], 0.f); }
                    }
                    uint4_ uv = {cvtpk(f[0], f[1]), cvtpk(f[2], f[3]),
                                 cvtpk(f[4], f[5]), cvtpk(f[6], f[7])};
                    v = __builtin_bit_cast(short8, uv);
                }
            }
            int r = dyi * XT + xl;
            int cs = (cic ^ ((r >> S) & (CINB - 1))) << 3;
            *(short8*)&T[r * CIN + cs] = v;
        }
    }
    __syncthreads();

    const int w = tid >> 6, lane = tid & 63;
    const int l15 = lane & 15, loct = lane >> 4;
    const int ocg = w & (OCG - 1);
    const int pxg = w / OCG;
    const int ocbase = ocg * OT * 16;
    const int pxbase = pxg * PT * 16;
    const int hsel = loct >> 1;
    (void)hsel;

    int bpt[PT];
#pragma unroll
    for (int pt = 0; pt < PT; ++pt) {
        int ppx = pxbase + pt * 16;
        bpt[pt] = (ppx >> LPXB) * XT + (ppx & (PXB - 1)) + l15;
    }

    const short* wl = wpack + (size_t)b * KPAD * COUT + ((size_t)loct * COUT + ocbase + l15) * 8;

    auto lA = [&](int s, short8* dst) {
        const short* ws = wl + (size_t)s * (4 * COUT * 8);
#pragma unroll
        for (int ot = 0; ot < OT; ++ot) dst[ot] = *(const short8*)&ws[ot * 128];
    };
    auto lB = [&](int s, short8* dst) {
        int Cs, cic;
        if constexpr (CIN == 64) {
            const int pos = s >> 1;
            Cs = (pos / 5) * (DIL * XT) + (pos % 5) * DIL;
            cic = (s & 1) * 4 + loct;
        } else if constexpr (CIN == 32) {
            Cs = (s / 5) * (DIL * XT) + (s % 5) * DIL;
            cic = loct;
        } else if constexpr (CIN == 8) {
            int pos = s * 4 + loct;
            if (pos > 24) pos = 24;
            Cs = (pos / 5) * (DIL * XT) + (pos % 5) * DIL;
            cic = 0;
        } else {   // CIN == 16
            const int p0 = (2 * s > 24) ? 24 : 2 * s;
            const int p1 = (2 * s + 1 > 24) ? 24 : 2 * s + 1;
            const int C0 = (p0 / 5) * (DIL * XT) + (p0 % 5) * DIL;
            const int C1 = (p1 / 5) * (DIL * XT) + (p1 % 5) * DIL;
            Cs = hsel ? C1 : C0;
            cic = loct & 1;
        }
#pragma unroll
        for (int pt = 0; pt < PT; ++pt) {
            int r = bpt[pt] + Cs;
            int chunk = cic ^ ((r >> S) & (CINB - 1));
            dst[pt] = *(const short8*)&T[r * CIN + (chunk << 3)];
        }
    };

    f32x4 acc[OT][PT] = {};
    short8 Acur[OT], Anx[OT], Bcur[PT];
    lA(0, Acur);
    lA(1, Anx);
    lB(0, Bcur);

    __builtin_amdgcn_s_setprio(1);
#pragma unroll
    for (int s = 0; s < NSTEP; ++s) {
        short8 An2[OT] = {}, Bn[PT] = {};
        if (s + 2 < NSTEP) lA(s + 2, An2);
        if (s + 1 < NSTEP) lB(s + 1, Bn);
#pragma unroll
        for (int ot = 0; ot < OT; ++ot)
#pragma unroll
            for (int pt = 0; pt < PT; ++pt)
                acc[ot][pt] = __builtin_amdgcn_mfma_f32_16x16x32_bf16(Acur[ot], Bcur[pt], acc[ot][pt], 0, 0, 0);
#pragma unroll
        for (int ot = 0; ot < OT; ++ot) { Acur[ot] = Anx[ot]; Anx[ot] = An2[ot]; }
#pragma unroll
        for (int pt = 0; pt < PT; ++pt) Bcur[pt] = Bn[pt];
    }
    __builtin_amdgcn_s_setprio(0);

    // ---- store bf16 ----
#pragma unroll
    for (int ot = 0; ot < OT; ++ot)
#pragma unroll
        for (int pt = 0; pt < PT; ++pt) {
            int ppx = pxbase + pt * 16;
            int gpx = (y0 + (ppx >> LPXB)) * WH + x0 + (ppx & (PXB - 1)) + l15;
            int oc = ocbase + ot * 16 + (loct << 2);
            uint2_ st = {cvtpk(acc[ot][pt][0], acc[ot][pt][1]),
                         cvtpk(acc[ot][pt][2], acc[ot][pt][3])};
            *(uint2_*)&outp[((size_t)b * WH * WH + gpx) * COUT + oc] = st;
        }

    __syncthreads();

    // ---- fused BN stats ----
    float sv[OT][4], qv[OT][4];
#pragma unroll
    for (int ot = 0; ot < OT; ++ot)
#pragma unroll
        for (int j = 0; j < 4; ++j) {
            float sa = 0.f, qa = 0.f;
#pragma unroll
            for (int pt = 0; pt < PT; ++pt) { float v = acc[ot][pt][j]; sa += v; qa += v * v; }
#pragma unroll
            for (int m = 1; m <= 8; m <<= 1) { sa += __shfl_xor(sa, m); qa += __shfl_xor(qa, m); }
            sv[ot][j] = sa; qv[ot][j] = qa;
        }
    if (l15 == 0) {
#pragma unroll
        for (int ot = 0; ot < OT; ++ot)
#pragma unroll
            for (int j = 0; j < 4; ++j) {
                int c = ocbase + ot * 16 + (loct << 2) + j;
                SP[(pxg * 2 + 0) * COUT + c] = sv[ot][j];
                SP[(pxg * 2 + 1) * COUT + c] = qv[ot][j];
            }
    }
    __syncthreads();
    if (tid < 2 * COUT) {
        int m = tid >> LOGC, c = tid & (COUT - 1);
        float v = 0.f;
#pragma unroll
        for (int g = 0; g < PXG; ++g) v += SP[(g * 2 + m) * COUT + c];
        atomicAdd(&partout[((size_t)b * 2 + m) * COUT + c], v);
    }
}

// ---------------- conv7 1x1 64->4 with bn6 fused: c6 raw bf16 -> c7 NHWC fp32 ----------------
__global__ void conv7k(const short* __restrict__ c6, const float* __restrict__ w7g,
                       const float* __restrict__ part, const float* __restrict__ sc,
                       const float* __restrict__ bi, float* __restrict__ c7) {
    __shared__ float wsm[256];
    __shared__ float GA[64], BE[64];
    const int b = blockIdx.y;
    const int t = threadIdx.x;
    wsm[t] = w7g[b * 256 + t];
    if (t < 64) {
        float S0 = part[((size_t)b * 2 + 0) * 64 + t];
        float Q0 = part[((size_t)b * 2 + 1) * 64 + t];
        float m = S0 * (1.f / 16384.f);
        float var = Q0 * (1.f / 16384.f) - m * m;
        float g = sc[t] * rsqrtf(var + 1e-5f);
        GA[t] = g;
        BE[t] = bi[t] - m * g;
    }
    __syncthreads();
    const int px = blockIdx.x * 64 + (t >> 2);
    const int q4 = t & 3;
    size_t base = ((size_t)b * 16384 + px) * 64 + q4 * 16;
    short8 s0 = *(const short8*)&c6[base];
    short8 s1 = *(const short8*)&c6[base + 8];
    f32x4 a = {0.f, 0.f, 0.f, 0.f};
#pragma unroll
    for (int ci = 0; ci < 8; ++ci) {
        float f0 = frombf(s0[ci]) * GA[q4 * 16 + ci] + BE[q4 * 16 + ci];
        float f1 = frombf(s1[ci]) * GA[q4 * 16 + 8 + ci] + BE[q4 * 16 + 8 + ci];
#pragma unroll
        for (int o = 0; o < 4; ++o) {
            a[o] = fmaf(f0, wsm[o * 64 + q4 * 16 + ci], a[o]);
            a[o] = fmaf(f1, wsm[o * 64 + q4 * 16 + 8 + ci], a[o]);
        }
    }
#pragma unroll
    for (int o = 0; o < 4; ++o) {
        a[o] += __shfl_xor(a[o], 1);
        a[o] += __shfl_xor(a[o], 2);
    }
    if (q4 == 0) *(f32x4*)&c7[((size_t)b * 16384 + px) * 4] = a;
}

// ---------------- bilinear x2 + residual -> NCHW out ----------------
__global__ void up2_add(const float* __restrict__ h, const float* __restrict__ xin,
                        float* __restrict__ outp, int total) {
    int stride = gridDim.x * blockDim.x;
    const float sc = 127.f / 255.f;
    for (int i = blockIdx.x * blockDim.x + threadIdx.x; i < total; i += stride) {
        int xo = i & 255, yo = (i >> 8) & 255, c = (i >> 16) & 3, b = i >> 18;
        float px = xo * sc, py = yo * sc;
        int x0 = (int)px, y0 = (int)py;
        float fx = px - x0, fy = py - y0;
        int x1 = min(x0 + 1, 127), y1 = min(y0 + 1, 127);
        const float* hb = h + ((size_t)b << 16);
        float v00 = hb[((y0 << 7) + x0) * 4 + c], v01 = hb[((y0 << 7) + x1) * 4 + c];
        float v10 = hb[((y1 << 7) + x0) * 4 + c], v11 = hb[((y1 << 7) + x1) * 4 + c];
        float vt = v00 + (v01 - v00) * fx;
        float vb = v10 + (v11 - v10) * fx;
        outp[i] = vt + (vb - vt) * fy + xin[i];
    }
}

extern "C" void kernel_launch(void* const* d_in, const int* in_sizes, int n_in,
                              void* d_out, int out_size, void* d_ws, size_t ws_size,
                              hipStream_t stream) {
    const float* x = (const float*)d_in[0];
    const int* action = (const int*)d_in[1];
    const float *W[7], *Bi[7], *bns[7], *bnb[7];
    for (int i = 0; i < 7; ++i) { W[i]   = (const float*)d_in[2 + 2 * i];
                                  Bi[i]  = (const float*)d_in[3 + 2 * i]; }
    for (int i = 0; i < 7; ++i) { bns[i] = (const float*)d_in[16 + 2 * i];
                                  bnb[i] = (const float*)d_in[17 + 2 * i]; }
    float* out = (float*)d_out;

    // ---- workspace carve (bytes) ----
    char* p = (char*)d_ws;
    auto carve = [&](size_t bytes) { char* r = p; p += (bytes + 255) & ~(size_t)255; return r; };
    float* w7g  = (float*)carve(256 * NB * 4);
    float* partAll = (float*)carve((size_t)NB * 2 * 228 * 4);
    float* p0 = partAll;                 // bn0, C=4
    float* p1 = p0 + NB * 2 * 4;         // conv1, C=16
    float* p2 = p1 + NB * 2 * 16;        // conv2, C=16
    float* p3 = p2 + NB * 2 * 16;        // conv3, C=32
    float* p4 = p3 + NB * 2 * 32;        // conv4, C=32
    float* p5 = p4 + NB * 2 * 32;        // conv5, C=64
    float* p6 = p5 + NB * 2 * 64;        // conv6, C=64
    short* wp1  = (short*)carve((size_t)224 * 16 * NB * 2);
    short* wp2  = (short*)carve((size_t)416 * 16 * NB * 2);
    short* wp3  = (short*)carve((size_t)416 * 32 * NB * 2);
    short* wp4  = (short*)carve((size_t)800 * 32 * NB * 2);
    short* wp5  = (short*)carve((size_t)800 * 64 * NB * 2);
    short* wp6  = (short*)carve((size_t)1600 * 64 * NB * 2);
    short* CB_A = (short*)carve((size_t)NB * 65536 * 16 * 2);   // c1 / c3 / c5
    short* CB_B = (short*)carve((size_t)NB * 65536 * 16 * 2);   // c2 / c4 / c6
    short* A0   = (short*)carve((size_t)NB * 65536 * 4 * 2);    // a2p
    float* C7   = (float*)carve((size_t)NB * 16384 * 4 * 4);

    hipMemsetAsync(partAll, 0, (size_t)NB * 2 * 228 * 4, stream);

    // ---- all weight gather/pack + bn0 stats in one launch ----
    pack_all<<<dim3(857, NB), 256, 0, stream>>>(
        W[1], Bi[1], W[2], Bi[2], W[3], Bi[3], W[4], Bi[4], W[5], Bi[5],
        W[0], Bi[0], W[6], Bi[6], action, wp2, wp3, wp4, wp5, wp6, wp1, w7g,
        x, p0);

    // ---- conv1 as MFMA (bn0 fused in staging, CIN=8 zero-padded) -> c1 (CB_A) + p1 ----
    convmf8<8, 16, 2, 256, 64, 8, 1, 8, 1, 1><<<dim3(4, 32, NB), 512, 0, stream>>>(
        (const short*)x, wp1, CB_A, p1, p0, bns[0], bnb[0], 1.f / 65536.f);

    // ---- conv2 (bn1+relu fused in staging) -> c2 (CB_B) + p2 ----
    convmf8<16, 16, 1, 256, 32, 16, 1, 8, 2><<<dim3(8, 16, NB), 512, 0, stream>>>(
        CB_A, wp2, CB_B, p2, p1, bns[1], bnb[1], 1.f / 65536.f);

    // ---- bn2 + avgpool -> a2p (A0) ----
    bnpool2<<<dim3(64, NB), 256, 0, stream>>>(CB_B, A0, p2, bns[2], bnb[2]);

    // ---- conv3 (input pre-normalized) -> c3 (CB_A) + p3 ----
    convmf8<16, 32, 2, 128, 32, 8, 1, 8, 0><<<dim3(4, 16, NB), 512, 0, stream>>>(
        A0, wp3, CB_A, p3, p2, bns[2], bnb[2], 1.f);

    // ---- conv4 (bn3+relu fused) -> c4 (CB_B) + p4 ----
    convmf8<32, 32, 1, 128, 64, 8, 1, 8, 2><<<dim3(2, 16, NB), 512, 0, stream>>>(
        CB_A, wp4, CB_B, p4, p3, bns[3], bnb[3], 1.f / 16384.f);

    // ---- conv5 (bn4 fused, no relu) -> c5 (CB_A) + p5; PXB=16 for occupancy ----
    convmf8<32, 64, 2, 128, 16, 8, 2, 8, 1><<<dim3(8, 16, NB), 512, 0, stream>>>(
        CB_B, wp5, CB_A, p5, p4, bns[4], bnb[4], 1.f / 16384.f);

    // ---- conv6 (bn5+relu fused) -> c6 (CB_B) + p6; PXB=16 for occupancy ----
    convmf8<64, 64, 1, 128, 16, 8, 2, 8, 2><<<dim3(8, 16, NB), 512, 0, stream>>>(
        CB_A, wp6, CB_B, p6, p5, bns[5], bnb[5], 1.f / 16384.f);

    // ---- conv7 (bn6 fused) -> C7; up2 + residual -> out ----
    conv7k<<<dim3(256, NB), 256, 0, stream>>>(CB_B, w7g, p6, bns[6], bnb[6], C7);
    up2_add<<<4096, 256, 0, stream>>>(C7, x, out, 4194304);
}

// Round 19
// 254.205 us; speedup vs baseline: 1.0719x; 1.0719x over previous
//
#include <hip/hip_runtime.h>

#define NB 16   // batch
#define NA 6    // actions

typedef __attribute__((ext_vector_type(8))) short short8;
typedef __attribute__((ext_vector_type(4))) short short4_;
typedef __attribute__((ext_vector_type(4))) float f32x4;
typedef __attribute__((ext_vector_type(4))) unsigned uint4_;
typedef __attribute__((ext_vector_type(2))) unsigned uint2_;

__device__ __forceinline__ short tobf(float f) {
    unsigned u = __builtin_bit_cast(unsigned, f);
    u += 0x7FFF + ((u >> 16) & 1);
    return (short)(u >> 16);
}
__device__ __forceinline__ float frombf(short s) {
    unsigned u = ((unsigned)(unsigned short)s) << 16;
    return __builtin_bit_cast(float, u);
}
// packed f32x2 -> bf16x2, RNE (single HW instruction)
__device__ __forceinline__ unsigned cvtpk(float a, float b) {
    unsigned r;
    asm("v_cvt_pk_bf16_f32 %0, %1, %2" : "=v"(r) : "v"(a), "v"(b));
    return r;
}

// ---------------- per-layer weight pack helper ----------------
template<int CIN, int COUT>
__device__ __forceinline__ void pack_one(const float* __restrict__ w, const float* __restrict__ bias,
                                         int a, int b, short* __restrict__ dst, int j) {
    constexpr int KTOT = 25 * CIN;
    constexpr int KPAD = (KTOT + 31) & ~31;
    if (j >= COUT * KPAD) return;
    int oc = j / KPAD, k = j - oc * KPAD;
    float v = 0.f;
    if (k < KTOT) {
        int pos = k / CIN, ci = k - pos * CIN;
        int ky = pos / 5, kx = pos - ky * 5;
        int od = ((oc * CIN + ci) * 5 + ky) * 5 + kx;
        v = w[(size_t)od * NA + a] + bias[od];
    }
    dst[((size_t)(b * (KPAD / 8) + (k >> 3)) * COUT + oc) * 8 + (k & 7)] = tobf(v);
}

// conv1: packed as CIN=8 (4 real channels + 4 zero), COUT=16, KTOT=200, KPAD=224
__device__ __forceinline__ void pack_one8(const float* __restrict__ w, const float* __restrict__ bias,
                                          int a, int b, short* __restrict__ dst, int j) {
    if (j >= 16 * 224) return;
    int oc = j / 224, k = j - oc * 224;
    float v = 0.f;
    if (k < 200) {
        int pos = k >> 3, ci = k & 7;
        if (ci < 4) {
            int ky = pos / 5, kx = pos - ky * 5;
            int od = ((oc * 4 + ci) * 5 + ky) * 5 + kx;
            v = w[(size_t)od * NA + a] + bias[od];
        }
    }
    dst[((size_t)(b * 28 + (k >> 3)) * 16 + oc) * 8 + (k & 7)] = tobf(v);
}

// ---------------- ALL weight gather/pack + bn0 stats partials in one launch ----------------
__global__ void pack_all(const float* __restrict__ w2, const float* __restrict__ b2,
                         const float* __restrict__ w3, const float* __restrict__ b3,
                         const float* __restrict__ w4, const float* __restrict__ b4,
                         const float* __restrict__ w5, const float* __restrict__ b5,
                         const float* __restrict__ w6, const float* __restrict__ b6,
                         const float* __restrict__ w1, const float* __restrict__ b1,
                         const float* __restrict__ w7, const float* __restrict__ b7,
                         const int* __restrict__ action,
                         short* __restrict__ d2, short* __restrict__ d3, short* __restrict__ d4,
                         short* __restrict__ d5, short* __restrict__ d6,
                         short* __restrict__ d1, float* __restrict__ g7,
                         const float* __restrict__ x, float* __restrict__ part0) {
    const int b = blockIdx.y;
    const int bx = blockIdx.x;
    const int t = threadIdx.x;
    if (bx >= 793) {
        // bn0 stats: 64 blocks per batch -> channel c, slice
        const int r = bx - 793;
        const int c = r >> 4, slice = r & 15;
        const float* p = x + (((size_t)(b * 4 + c)) << 16) + slice * 4096;
        float sum = 0.f, sq = 0.f;
        for (int i = t * 4; i < 4096; i += 1024) {
            float4 v = *(const float4*)(p + i);
            sum += (v.x + v.y) + (v.z + v.w);
            sq  += (v.x * v.x + v.y * v.y) + (v.z * v.z + v.w * v.w);
        }
#pragma unroll
        for (int off = 32; off > 0; off >>= 1) {
            sum += __shfl_down(sum, off);
            sq  += __shfl_down(sq, off);
        }
        __shared__ float ssum[4], ssq[4];
        int wv = t >> 6;
        if ((t & 63) == 0) { ssum[wv] = sum; ssq[wv] = sq; }
        __syncthreads();
        if (t == 0) {
            float S = ssum[0] + ssum[1] + ssum[2] + ssum[3];
            float Q = ssq[0] + ssq[1] + ssq[2] + ssq[3];
            atomicAdd(&part0[((size_t)b * 2 + 0) * 4 + c], S);
            atomicAdd(&part0[((size_t)b * 2 + 1) * 4 + c], Q);
        }
        return;
    }
    const int a = action[b];
    if (bx < 26)       pack_one<16, 16>(w2, b2, a, b, d2, bx * 256 + t);
    else if (bx < 78)  pack_one<16, 32>(w3, b3, a, b, d3, (bx - 26) * 256 + t);
    else if (bx < 178) pack_one<32, 32>(w4, b4, a, b, d4, (bx - 78) * 256 + t);
    else if (bx < 378) pack_one<32, 64>(w5, b5, a, b, d5, (bx - 178) * 256 + t);
    else if (bx < 778) pack_one<64, 64>(w6, b6, a, b, d6, (bx - 378) * 256 + t);
    else if (bx < 792) pack_one8(w1, b1, a, b, d1, (bx - 778) * 256 + t);
    else               { g7[(size_t)b * 256 + t] = w7[(size_t)t * NA + a] + b7[t]; }
}

// ---------------- inline BN finalize for 8 channels (from part sums) ----------------
template<int C>
__device__ __forceinline__ void bn_fin8(const float* __restrict__ part,
                                        const float* __restrict__ sc,
                                        const float* __restrict__ bi,
                                        int b, int c0, float invN, f32x4* g, f32x4* e) {
#pragma unroll
    for (int h = 0; h < 2; ++h) {
        f32x4 Sv = *(const f32x4*)&part[((size_t)b * 2 + 0) * C + c0 + h * 4];
        f32x4 Qv = *(const f32x4*)&part[((size_t)b * 2 + 1) * C + c0 + h * 4];
        f32x4 scv = *(const f32x4*)&sc[c0 + h * 4];
        f32x4 biv = *(const f32x4*)&bi[c0 + h * 4];
#pragma unroll
        for (int j = 0; j < 4; ++j) {
            float m = Sv[j] * invN;
            float var = Qv[j] * invN - m * m;
            float gg = scv[j] * rsqrtf(var + 1e-5f);
            g[h][j] = gg;
            e[h][j] = biv[j] - m * gg;
        }
    }
}

// ---------------- bn2 apply + 2x2 avgpool, bf16 -> bf16 (finalize inline) ----------------
__global__ void bnpool2(const short* __restrict__ in, short* __restrict__ out,
                        const float* __restrict__ part, const float* __restrict__ sc,
                        const float* __restrict__ bi) {
    const int b = blockIdx.y;
    const int c8 = threadIdx.x & 1;
    const int c0 = c8 * 8;
    f32x4 g[2], e[2];
    bn_fin8<16>(part, sc, bi, b, c0, 1.f / 65536.f, g, e);
    const size_t bin = (size_t)b * 65536 * 16;
    const size_t bout = (size_t)b * 16384 * 16;
    int total = 16384 * 2;
    int stride = gridDim.x * 256;
    for (int i = blockIdx.x * 256 + threadIdx.x; i < total; i += stride) {
        int opx = i >> 1;
        int ho = opx >> 7, wo = opx & 127;
        size_t p0 = bin + ((size_t)(ho * 2) * 256 + wo * 2) * 16 + c0;
        short8 v00 = *(const short8*)&in[p0];
        short8 v01 = *(const short8*)&in[p0 + 16];
        short8 v10 = *(const short8*)&in[p0 + 4096];
        short8 v11 = *(const short8*)&in[p0 + 4112];
        float f[8];
#pragma unroll
        for (int h = 0; h < 2; ++h)
#pragma unroll
            for (int j = 0; j < 4; ++j) {
                int k = h * 4 + j;
                float fv = (frombf(v00[k]) + frombf(v01[k]) + frombf(v10[k]) + frombf(v11[k])) * 0.25f;
                f[k] = fv * g[h][j] + e[h][j];
            }
        uint4_ vo = {cvtpk(f[0], f[1]), cvtpk(f[2], f[3]), cvtpk(f[4], f[5]), cvtpk(f[6], f[7])};
        *(uint4_*)&out[bout + (size_t)i * 8] = vo;
    }
}

// ---------------- MFMA 5x5 conv v10 (16x16x32): unified contiguous-row staging for all DIL ----------------
// APPLY: 0 = none, 1 = affine, 2 = affine+relu; INMODE: 1 = fp32 NCHW C=4 input, bn0, widen to C=8
template<int CIN, int COUT, int DIL, int WH, int PXB, int ROWS, int OCG, int WAVES, int APPLY, int INMODE = 0>
__global__ void __launch_bounds__(WAVES * 64) convmf8(const short* __restrict__ in,
                                                      const short* __restrict__ wpack,
                                                      short* __restrict__ outp,
                                                      float* __restrict__ partout,
                                                      const float* __restrict__ partin,
                                                      const float* __restrict__ psc,
                                                      const float* __restrict__ pbi,
                                                      float invN) {
    constexpr int PAD   = 2 * DIL;
    constexpr int XT    = PXB + 4 * DIL + 1;
    constexpr int LROWS = ROWS + 4 * DIL;               // contiguous halo rows
    constexpr int KTOT  = 25 * CIN;
    constexpr int KPAD  = (KTOT + 31) & ~31;
    constexpr int NSTEP = KPAD / 32;
    constexpr int CINB  = CIN / 8;
    constexpr int S     = (CIN == 64) ? 0 : (CIN == 32) ? 1 : 2;
    constexpr int NTHR  = WAVES * 64;
    constexpr int PXG   = WAVES / OCG;
    constexpr int OT    = COUT / 16 / OCG;
    constexpr int PT    = ROWS * PXB / (16 * PXG);
    constexpr int LPXB  = (PXB == 32) ? 5 : (PXB == 64) ? 6 : 7;
    constexpr int LOGC  = (COUT == 64) ? 6 : (COUT == 32) ? 5 : 4;
    constexpr int CREAL = (INMODE == 1) ? 4 : CIN;
    constexpr int TBYTES = LROWS * XT * CIN * 2;
    static_assert(PXG * 2 * COUT * 4 <= TBYTES, "SP alias fits in T");
    static_assert(NSTEP >= 2, "pipeline depth");
    static_assert(PT * 16 * PXG == ROWS * PXB, "px cover");

    __shared__ __align__(16) char smem[TBYTES + 2 * 64 * 4];
    short* T  = (short*)smem;
    float* GA = (float*)(smem + TBYTES);
    float* BE = GA + 64;
    float* SP = (float*)smem;

    const int b   = blockIdx.z;
    const int y0  = blockIdx.y * ROWS;
    const int x0  = blockIdx.x * PXB;
    const int tid = threadIdx.x;

    if (APPLY) {
        if (tid < CREAL) {
            float S0 = partin[((size_t)b * 2 + 0) * CREAL + tid];
            float Q0 = partin[((size_t)b * 2 + 1) * CREAL + tid];
            float m = S0 * invN;
            float var = Q0 * invN - m * m;
            float g = psc[tid] * rsqrtf(var + 1e-5f);
            GA[tid] = g;
            BE[tid] = pbi[tid] - m * g;
        }
        __syncthreads();
    }

    if constexpr (INMODE == 1) {
        const float* xf = (const float*)in + ((size_t)b << 18);
        float g0 = GA[0], g1 = GA[1], g2 = GA[2], g3 = GA[3];
        float e0 = BE[0], e1 = BE[1], e2 = BE[2], e3 = BE[3];
        for (int idx = tid; idx < LROWS * XT; idx += NTHR) {
            int dyi = idx / XT, xl = idx - dyi * XT;
            int gy = y0 + dyi - PAD;
            int gx = x0 - PAD + xl;
            short8 v = {};
            if ((unsigned)gy < (unsigned)WH && (unsigned)gx < (unsigned)WH) {
                int o = (gy << 8) + gx;
                float f0 = xf[o] * g0 + e0;
                float f1 = xf[o + 65536] * g1 + e1;
                float f2 = xf[o + 131072] * g2 + e2;
                float f3 = xf[o + 196608] * g3 + e3;
                uint4_ uv = {cvtpk(f0, f1), cvtpk(f2, f3), 0u, 0u};
                v = __builtin_bit_cast(short8, uv);
            }
            *(short8*)&T[idx * CIN] = v;
        }
    } else {
        const short* inb = in + (size_t)b * WH * WH * CIN;
        for (int idx = tid; idx < LROWS * XT * CINB; idx += NTHR) {
            int dyi = idx / (XT * CINB);
            int rem = idx - dyi * (XT * CINB);
            int xl = rem / CINB, cic = rem - xl * CINB;
            int gy = y0 + dyi - PAD;
            int gx = x0 - PAD + xl;
            short8 v = {};
            if ((unsigned)gy < (unsigned)WH && (unsigned)gx < (unsigned)WH) {
                v = *(const short8*)&inb[((size_t)gy * WH + gx) * CIN + cic * 8];
                if (APPLY) {
                    float f[8];
#pragma unroll
                    for (int j = 0; j < 8; ++j) f[j] = frombf(v[j]);
                    f32x4 g0 = *(const f32x4*)&GA[cic * 8];
                    f32x4 g1 = *(const f32x4*)&GA[cic * 8 + 4];
                    f32x4 e0 = *(const f32x4*)&BE[cic * 8];
                    f32x4 e1 = *(const f32x4*)&BE[cic * 8 + 4];
#pragma unroll
                    for (int j = 0; j < 4; ++j) {
                        f[j]     = f[j]     * g0[j] + e0[j];
                        f[4 + j] = f[4 + j] * g1[j] + e1[j];
                        if (APPLY == 2) { f[j] = fmaxf(f[j], 0.f); f[4 + j] = fmaxf(f[4 + j], 0.f); }
                    }
                    uint4_ uv = {cvtpk(f[0], f[1]), cvtpk(f[2], f[3]),
                                 cvtpk(f[4], f[5]), cvtpk(f[6], f[7])};
                    v = __builtin_bit_cast(short8, uv);
                }
            }
            int r = dyi * XT + xl;
            int cs = (cic ^ ((r >> S) & (CINB - 1))) << 3;
            *(short8*)&T[r * CIN + cs] = v;
        }
    }
    __syncthreads();

    const int w = tid >> 6, lane = tid & 63;
    const int l15 = lane & 15, loct = lane >> 4;
    const int ocg = w & (OCG - 1);
    const int pxg = w / OCG;
    const int ocbase = ocg * OT * 16;
    const int pxbase = pxg * PT * 16;
    const int hsel = loct >> 1;
    (void)hsel;

    int bpt[PT];
#pragma unroll
    for (int pt = 0; pt < PT; ++pt) {
        int ppx = pxbase + pt * 16;
        bpt[pt] = (ppx >> LPXB) * XT + (ppx & (PXB - 1)) + l15;
    }

    const short* wl = wpack + (size_t)b * KPAD * COUT + ((size_t)loct * COUT + ocbase + l15) * 8;

    auto lA = [&](int s, short8* dst) {
        const short* ws = wl + (size_t)s * (4 * COUT * 8);
#pragma unroll
        for (int ot = 0; ot < OT; ++ot) dst[ot] = *(const short8*)&ws[ot * 128];
    };
    auto lB = [&](int s, short8* dst) {
        int Cs, cic;
        if constexpr (CIN == 64) {
            const int pos = s >> 1;
            Cs = (pos / 5) * (DIL * XT) + (pos % 5) * DIL;
            cic = (s & 1) * 4 + loct;
        } else if constexpr (CIN == 32) {
            Cs = (s / 5) * (DIL * XT) + (s % 5) * DIL;
            cic = loct;
        } else if constexpr (CIN == 8) {
            int pos = s * 4 + loct;
            if (pos > 24) pos = 24;
            Cs = (pos / 5) * (DIL * XT) + (pos % 5) * DIL;
            cic = 0;
        } else {   // CIN == 16
            const int p0 = (2 * s > 24) ? 24 : 2 * s;
            const int p1 = (2 * s + 1 > 24) ? 24 : 2 * s + 1;
            const int C0 = (p0 / 5) * (DIL * XT) + (p0 % 5) * DIL;
            const int C1 = (p1 / 5) * (DIL * XT) + (p1 % 5) * DIL;
            Cs = hsel ? C1 : C0;
            cic = loct & 1;
        }
#pragma unroll
        for (int pt = 0; pt < PT; ++pt) {
            int r = bpt[pt] + Cs;
            int chunk = cic ^ ((r >> S) & (CINB - 1));
            dst[pt] = *(const short8*)&T[r * CIN + (chunk << 3)];
        }
    };

    f32x4 acc[OT][PT] = {};
    short8 Acur[OT], Anx[OT], Bcur[PT];
    lA(0, Acur);
    lA(1, Anx);
    lB(0, Bcur);

    __builtin_amdgcn_s_setprio(1);
#pragma unroll
    for (int s = 0; s < NSTEP; ++s) {
        short8 An2[OT] = {}, Bn[PT] = {};
        if (s + 2 < NSTEP) lA(s + 2, An2);
        if (s + 1 < NSTEP) lB(s + 1, Bn);
#pragma unroll
        for (int ot = 0; ot < OT; ++ot)
#pragma unroll
            for (int pt = 0; pt < PT; ++pt)
                acc[ot][pt] = __builtin_amdgcn_mfma_f32_16x16x32_bf16(Acur[ot], Bcur[pt], acc[ot][pt], 0, 0, 0);
#pragma unroll
        for (int ot = 0; ot < OT; ++ot) { Acur[ot] = Anx[ot]; Anx[ot] = An2[ot]; }
#pragma unroll
        for (int pt = 0; pt < PT; ++pt) Bcur[pt] = Bn[pt];
    }
    __builtin_amdgcn_s_setprio(0);

    // ---- store bf16 ----
#pragma unroll
    for (int ot = 0; ot < OT; ++ot)
#pragma unroll
        for (int pt = 0; pt < PT; ++pt) {
            int ppx = pxbase + pt * 16;
            int gpx = (y0 + (ppx >> LPXB)) * WH + x0 + (ppx & (PXB - 1)) + l15;
            int oc = ocbase + ot * 16 + (loct << 2);
            uint2_ st = {cvtpk(acc[ot][pt][0], acc[ot][pt][1]),
                         cvtpk(acc[ot][pt][2], acc[ot][pt][3])};
            *(uint2_*)&outp[((size_t)b * WH * WH + gpx) * COUT + oc] = st;
        }

    __syncthreads();

    // ---- fused BN stats ----
    float sv[OT][4], qv[OT][4];
#pragma unroll
    for (int ot = 0; ot < OT; ++ot)
#pragma unroll
        for (int j = 0; j < 4; ++j) {
            float sa = 0.f, qa = 0.f;
#pragma unroll
            for (int pt = 0; pt < PT; ++pt) { float v = acc[ot][pt][j]; sa += v; qa += v * v; }
#pragma unroll
            for (int m = 1; m <= 8; m <<= 1) { sa += __shfl_xor(sa, m); qa += __shfl_xor(qa, m); }
            sv[ot][j] = sa; qv[ot][j] = qa;
        }
    if (l15 == 0) {
#pragma unroll
        for (int ot = 0; ot < OT; ++ot)
#pragma unroll
            for (int j = 0; j < 4; ++j) {
                int c = ocbase + ot * 16 + (loct << 2) + j;
                SP[(pxg * 2 + 0) * COUT + c] = sv[ot][j];
                SP[(pxg * 2 + 1) * COUT + c] = qv[ot][j];
            }
    }
    __syncthreads();
    if (tid < 2 * COUT) {
        int m = tid >> LOGC, c = tid & (COUT - 1);
        float v = 0.f;
#pragma unroll
        for (int g = 0; g < PXG; ++g) v += SP[(g * 2 + m) * COUT + c];
        atomicAdd(&partout[((size_t)b * 2 + m) * COUT + c], v);
    }
}

// ---------------- conv7 1x1 64->4 with bn6 fused: c6 raw bf16 -> c7 NHWC fp32 ----------------
__global__ void conv7k(const short* __restrict__ c6, const float* __restrict__ w7g,
                       const float* __restrict__ part, const float* __restrict__ sc,
                       const float* __restrict__ bi, float* __restrict__ c7) {
    __shared__ float wsm[256];
    __shared__ float GA[64], BE[64];
    const int b = blockIdx.y;
    const int t = threadIdx.x;
    wsm[t] = w7g[b * 256 + t];
    if (t < 64) {
        float S0 = part[((size_t)b * 2 + 0) * 64 + t];
        float Q0 = part[((size_t)b * 2 + 1) * 64 + t];
        float m = S0 * (1.f / 16384.f);
        float var = Q0 * (1.f / 16384.f) - m * m;
        float g = sc[t] * rsqrtf(var + 1e-5f);
        GA[t] = g;
        BE[t] = bi[t] - m * g;
    }
    __syncthreads();
    const int px = blockIdx.x * 64 + (t >> 2);
    const int q4 = t & 3;
    size_t base = ((size_t)b * 16384 + px) * 64 + q4 * 16;
    short8 s0 = *(const short8*)&c6[base];
    short8 s1 = *(const short8*)&c6[base + 8];
    f32x4 a = {0.f, 0.f, 0.f, 0.f};
#pragma unroll
    for (int ci = 0; ci < 8; ++ci) {
        float f0 = frombf(s0[ci]) * GA[q4 * 16 + ci] + BE[q4 * 16 + ci];
        float f1 = frombf(s1[ci]) * GA[q4 * 16 + 8 + ci] + BE[q4 * 16 + 8 + ci];
#pragma unroll
        for (int o = 0; o < 4; ++o) {
            a[o] = fmaf(f0, wsm[o * 64 + q4 * 16 + ci], a[o]);
            a[o] = fmaf(f1, wsm[o * 64 + q4 * 16 + 8 + ci], a[o]);
        }
    }
#pragma unroll
    for (int o = 0; o < 4; ++o) {
        a[o] += __shfl_xor(a[o], 1);
        a[o] += __shfl_xor(a[o], 2);
    }
    if (q4 == 0) *(f32x4*)&c7[((size_t)b * 16384 + px) * 4] = a;
}

// ---------------- bilinear x2 + residual -> NCHW out ----------------
__global__ void up2_add(const float* __restrict__ h, const float* __restrict__ xin,
                        float* __restrict__ outp, int total) {
    int stride = gridDim.x * blockDim.x;
    const float sc = 127.f / 255.f;
    for (int i = blockIdx.x * blockDim.x + threadIdx.x; i < total; i += stride) {
        int xo = i & 255, yo = (i >> 8) & 255, c = (i >> 16) & 3, b = i >> 18;
        float px = xo * sc, py = yo * sc;
        int x0 = (int)px, y0 = (int)py;
        float fx = px - x0, fy = py - y0;
        int x1 = min(x0 + 1, 127), y1 = min(y0 + 1, 127);
        const float* hb = h + ((size_t)b << 16);
        float v00 = hb[((y0 << 7) + x0) * 4 + c], v01 = hb[((y0 << 7) + x1) * 4 + c];
        float v10 = hb[((y1 << 7) + x0) * 4 + c], v11 = hb[((y1 << 7) + x1) * 4 + c];
        float vt = v00 + (v01 - v00) * fx;
        float vb = v10 + (v11 - v10) * fx;
        outp[i] = vt + (vb - vt) * fy + xin[i];
    }
}

extern "C" void kernel_launch(void* const* d_in, const int* in_sizes, int n_in,
                              void* d_out, int out_size, void* d_ws, size_t ws_size,
                              hipStream_t stream) {
    const float* x = (const float*)d_in[0];
    const int* action = (const int*)d_in[1];
    const float *W[7], *Bi[7], *bns[7], *bnb[7];
    for (int i = 0; i < 7; ++i) { W[i]   = (const float*)d_in[2 + 2 * i];
                                  Bi[i]  = (const float*)d_in[3 + 2 * i]; }
    for (int i = 0; i < 7; ++i) { bns[i] = (const float*)d_in[16 + 2 * i];
                                  bnb[i] = (const float*)d_in[17 + 2 * i]; }
    float* out = (float*)d_out;

    // ---- workspace carve (bytes) ----
    char* p = (char*)d_ws;
    auto carve = [&](size_t bytes) { char* r = p; p += (bytes + 255) & ~(size_t)255; return r; };
    float* w7g  = (float*)carve(256 * NB * 4);
    float* partAll = (float*)carve((size_t)NB * 2 * 228 * 4);
    float* p0 = partAll;                 // bn0, C=4
    float* p1 = p0 + NB * 2 * 4;         // conv1, C=16
    float* p2 = p1 + NB * 2 * 16;        // conv2, C=16
    float* p3 = p2 + NB * 2 * 16;        // conv3, C=32
    float* p4 = p3 + NB * 2 * 32;        // conv4, C=32
    float* p5 = p4 + NB * 2 * 32;        // conv5, C=64
    float* p6 = p5 + NB * 2 * 64;        // conv6, C=64
    short* wp1  = (short*)carve((size_t)224 * 16 * NB * 2);
    short* wp2  = (short*)carve((size_t)416 * 16 * NB * 2);
    short* wp3  = (short*)carve((size_t)416 * 32 * NB * 2);
    short* wp4  = (short*)carve((size_t)800 * 32 * NB * 2);
    short* wp5  = (short*)carve((size_t)800 * 64 * NB * 2);
    short* wp6  = (short*)carve((size_t)1600 * 64 * NB * 2);
    short* CB_A = (short*)carve((size_t)NB * 65536 * 16 * 2);   // c1 / c3 / c5
    short* CB_B = (short*)carve((size_t)NB * 65536 * 16 * 2);   // c2 / c4 / c6
    short* A0   = (short*)carve((size_t)NB * 65536 * 4 * 2);    // a2p
    float* C7   = (float*)carve((size_t)NB * 16384 * 4 * 4);

    hipMemsetAsync(partAll, 0, (size_t)NB * 2 * 228 * 4, stream);

    // ---- all weight gather/pack + bn0 stats in one launch ----
    pack_all<<<dim3(857, NB), 256, 0, stream>>>(
        W[1], Bi[1], W[2], Bi[2], W[3], Bi[3], W[4], Bi[4], W[5], Bi[5],
        W[0], Bi[0], W[6], Bi[6], action, wp2, wp3, wp4, wp5, wp6, wp1, w7g,
        x, p0);

    // ---- conv1 as MFMA (bn0 fused in staging, CIN=8 zero-padded) -> c1 (CB_A) + p1 ----
    convmf8<8, 16, 2, 256, 64, 8, 1, 8, 1, 1><<<dim3(4, 32, NB), 512, 0, stream>>>(
        (const short*)x, wp1, CB_A, p1, p0, bns[0], bnb[0], 1.f / 65536.f);

    // ---- conv2 (bn1+relu fused in staging) -> c2 (CB_B) + p2 ----
    convmf8<16, 16, 1, 256, 32, 16, 1, 8, 2><<<dim3(8, 16, NB), 512, 0, stream>>>(
        CB_A, wp2, CB_B, p2, p1, bns[1], bnb[1], 1.f / 65536.f);

    // ---- bn2 + avgpool -> a2p (A0) ----
    bnpool2<<<dim3(64, NB), 256, 0, stream>>>(CB_B, A0, p2, bns[2], bnb[2]);

    // ---- conv3 (input pre-normalized) -> c3 (CB_A) + p3 ----
    convmf8<16, 32, 2, 128, 32, 8, 1, 8, 0><<<dim3(4, 16, NB), 512, 0, stream>>>(
        A0, wp3, CB_A, p3, p2, bns[2], bnb[2], 1.f);

    // ---- conv4 (bn3+relu fused) -> c4 (CB_B) + p4 ----
    convmf8<32, 32, 1, 128, 64, 8, 1, 8, 2><<<dim3(2, 16, NB), 512, 0, stream>>>(
        CB_A, wp4, CB_B, p4, p3, bns[3], bnb[3], 1.f / 16384.f);

    // ---- conv5 (bn4 fused, no relu) -> c5 (CB_A) + p5; OCG=2 (OT=2, PT=4) ----
    convmf8<32, 64, 2, 128, 32, 8, 2, 8, 1><<<dim3(4, 16, NB), 512, 0, stream>>>(
        CB_B, wp5, CB_A, p5, p4, bns[4], bnb[4], 1.f / 16384.f);

    // ---- conv6 (bn5+relu fused) -> c6 (CB_B) + p6; OCG=2 (OT=2, PT=4) ----
    convmf8<64, 64, 1, 128, 32, 8, 2, 8, 2><<<dim3(4, 16, NB), 512, 0, stream>>>(
        CB_A, wp6, CB_B, p6, p5, bns[5], bnb[5], 1.f / 16384.f);

    // ---- conv7 (bn6 fused) -> C7; up2 + residual -> out ----
    conv7k<<<dim3(256, NB), 256, 0, stream>>>(CB_B, w7g, p6, bns[6], bnb[6], C7);
    up2_add<<<4096, 256, 0, stream>>>(C7, x, out, 4194304);
}